// Round 2
// baseline (153.926 us; speedup 1.0000x reference)
//
#include <hip/hip_runtime.h>
#include <stdint.h>

#define BS 256
#define SCAN_T 1024

// ---- helpers ----
__device__ __forceinline__ unsigned f2key(float f) {
    unsigned u = __float_as_uint(f);
    return (u & 0x80000000u) ? ~u : (u | 0x80000000u);
}
__device__ __forceinline__ float key2f(unsigned k) {
    unsigned u = (k & 0x80000000u) ? (k & 0x7FFFFFFFu) : ~k;
    return __uint_as_float(u);
}
__device__ __forceinline__ float s_val(const float* score, const int* track, int i) {
    return track[i] ? 0.0f : score[i];
}
// searchsorted(row_splits, i, 'right') - 1 over B+1 entries
__device__ __forceinline__ int find_seg(const int* rs, int B, int i) {
    int l = 0, h = B + 1;
    while (l < h) { int m = (l + h) >> 1; if (rs[m] <= i) l = m + 1; else h = m; }
    return l - 1;
}

// key(+inf) = 0xFF800000
#define KEY_INF 0xFF800000u

// All threads of the block return the threshold, recomputed from seg_min
// (B is small; seg_min stays L2-hot). Requires blockDim.x >= 64.
__device__ __forceinline__ float block_threshold(const unsigned* __restrict__ seg_min, int B) {
    __shared__ float shT;
    if (threadIdx.x < 64) {
        float m = -INFINITY;
        for (int t = threadIdx.x; t < B; t += 64) m = fmaxf(m, key2f(seg_min[t]));
        for (int d = 32; d > 0; d >>= 1) m = fmaxf(m, __shfl_xor(m, d));
        if (threadIdx.x == 0) {
            const float invR = 1.0f / 10.0f;
            shT = (m < invR) ? invR : (m + 1e-7f);
        }
    }
    __syncthreads();
    return shT;
}

__global__ void k_init(unsigned* seg_min, int B) {
    int t = blockIdx.x * blockDim.x + threadIdx.x;
    if (t < B) seg_min[t] = KEY_INF;
}

__global__ void k_segmin(const float* __restrict__ score, const int* __restrict__ track,
                         const int* __restrict__ rs, int N, int B,
                         unsigned* __restrict__ seg_min) {
    __shared__ unsigned smin[1024];
    int i = blockIdx.x * blockDim.x + threadIdx.x;
    if (B <= 1024) {
        for (int t = threadIdx.x; t < B; t += blockDim.x) smin[t] = KEY_INF;
        __syncthreads();
        if (i < N) {
            float s = s_val(score, track, i);
            int seg = find_seg(rs, B, i);
            atomicMin(&smin[seg], f2key(s));
        }
        __syncthreads();
        for (int t = threadIdx.x; t < B; t += blockDim.x)
            if (smin[t] != KEY_INF) atomicMin(&seg_min[t], smin[t]);
    } else {
        if (i < N) {
            float s = s_val(score, track, i);
            int seg = find_seg(rs, B, i);
            atomicMin(&seg_min[seg], f2key(s));
        }
    }
}

__global__ void k_count(const float* __restrict__ score, const int* __restrict__ track,
                        const unsigned* __restrict__ seg_min, int B,
                        int N, int* __restrict__ blk_cnt) {
    float T = block_threshold(seg_min, B);
    int i = blockIdx.x * blockDim.x + threadIdx.x;
    bool pred = (i < N) ? (s_val(score, track, i) <= T) : false;
    unsigned long long b = __ballot(pred);
    __shared__ int wc[BS / 64];
    int w = threadIdx.x >> 6;
    if ((threadIdx.x & 63) == 0) wc[w] = __popcll(b);
    __syncthreads();
    if (threadIdx.x == 0) {
        int s = 0;
        for (int j = 0; j < BS / 64; ++j) s += wc[j];
        blk_cnt[blockIdx.x] = s;
    }
}

// single block: exclusive scan of blk[] in place; writes total + scalar outputs
__global__ void k_scan(int* __restrict__ blk, int nb, int* __restrict__ total,
                       float* __restrict__ out_old, float* __restrict__ out_nsel, int N) {
    __shared__ int sh[SCAN_T];
    int t = threadIdx.x;
    int ept = (nb + SCAN_T - 1) / SCAN_T;
    long base = (long)t * ept;
    int mySum = 0;
    for (int j = 0; j < ept; ++j) {
        long idx = base + j;
        if (idx < nb) mySum += blk[idx];
    }
    sh[t] = mySum;
    __syncthreads();
    for (int d = 1; d < SCAN_T; d <<= 1) {
        int add = (t >= d) ? sh[t - d] : 0;
        __syncthreads();
        sh[t] += add;
        __syncthreads();
    }
    int run = sh[t] - mySum;  // exclusive base for this thread
    for (int j = 0; j < ept; ++j) {
        long idx = base + j;
        if (idx < nb) { int c = blk[idx]; blk[idx] = run; run += c; }
    }
    if (t == SCAN_T - 1) {
        int tot = sh[SCAN_T - 1];
        *total = tot;
        *out_nsel = (float)tot;
        *out_old = (float)N;
    }
}

// one wave per b in [0, B]: new_rs[b] = #selected with i < row_splits[b]
__global__ void k_newrs(const float* __restrict__ score, const int* __restrict__ track,
                        const unsigned* __restrict__ seg_min, int B,
                        const int* __restrict__ rs,
                        const int* __restrict__ blk_off, const int* __restrict__ total,
                        int nb, float* __restrict__ out_newrs) {
    float T = block_threshold(seg_min, B);
    int b = blockIdx.x;
    int pos = rs[b];
    int blkI = pos / BS;
    int start = blkI * BS;
    int cnt = 0;
    for (int i = start + (int)threadIdx.x; i < pos; i += 64) {
        if (s_val(score, track, i) <= T) cnt++;
    }
    for (int d = 32; d > 0; d >>= 1) cnt += __shfl_down(cnt, d);
    if (threadIdx.x == 0) {
        int off = (blkI < nb) ? blk_off[blkI] : *total;
        out_newrs[b] = (float)(off + cnt);
    }
}

// Fused select: compute mask, write indices output, and (VEC path) copy the
// selected x rows to their compacted destination with fully-coalesced stores.
template <bool VEC>
__global__ void k_select(const float* __restrict__ score, const int* __restrict__ track,
                         const unsigned* __restrict__ seg_min, int B,
                         const int* __restrict__ blk_off, const int* __restrict__ total,
                         int N, int Fv,
                         const float4* __restrict__ x4, float4* __restrict__ out4,
                         float* __restrict__ out_idx) {
    float T = block_threshold(seg_min, B);
    int i = blockIdx.x * BS + threadIdx.x;
    bool pred = (i < N) ? (s_val(score, track, i) <= T) : false;
    unsigned long long b = __ballot(pred);
    int lane = threadIdx.x & 63;
    int w = threadIdx.x >> 6;
    __shared__ int wc[BS / 64];
    __shared__ int rows[BS];
    if (lane == 0) wc[w] = __popcll(b);
    __syncthreads();
    int waveBase = 0;
    for (int j = 0; j < w; ++j) waveBase += wc[j];
    int cnt = 0;
    for (int j = 0; j < BS / 64; ++j) cnt += wc[j];
    int base = blk_off[blockIdx.x];
    if (pred) {
        int rank = waveBase + __popcll(b & ((1ULL << (unsigned)lane) - 1ULL));
        rows[rank] = i;
        out_idx[base + rank] = (float)i;
    }
    if (i < N && i >= *total) out_idx[i] = -1.0f;
    if (VEC) {
        __syncthreads();
        // cooperative row copy: Fv lanes per row, rows dense at [base, base+cnt)
        int r0 = threadIdx.x / Fv;
        int c  = threadIdx.x - r0 * Fv;
        int rstep = BS / Fv;
        for (int r = r0; r < cnt; r += rstep) {
            out4[(long)(base + r) * Fv + c] = x4[(long)rows[r] * Fv + c];
        }
    }
}

// zero the tail rows [n_sel, N) of the output matrix — pure streaming store
__global__ void k_tailzero(const int* __restrict__ total, long totElems, int Fv,
                           float4* __restrict__ out4) {
    long t = (long)blockIdx.x * BS + threadIdx.x;
    if (t >= totElems) return;
    if (t < (long)(*total) * Fv) return;
    out4[t] = make_float4(0.0f, 0.0f, 0.0f, 0.0f);
}

// scalar fallback (F % 4 != 0 or BS % Fv != 0): full elementwise gather
__global__ void k_gather1(const float* __restrict__ x, const float* __restrict__ idxf,
                          int N, int F, float* __restrict__ out) {
    long t = (long)blockIdx.x * blockDim.x + threadIdx.x;
    long tot = (long)N * F;
    if (t >= tot) return;
    int p = (int)(t / F);
    int c = (int)(t - (long)p * F);
    float f = idxf[p];
    float v = 0.0f;
    if (f >= 0.0f) {
        int idx = (int)f;
        v = x[(long)idx * F + c];
    }
    out[t] = v;
}

extern "C" void kernel_launch(void* const* d_in, const int* in_sizes, int n_in,
                              void* d_out, int out_size, void* d_ws, size_t ws_size,
                              hipStream_t stream) {
    const float* x     = (const float*)d_in[0];
    const float* score = (const float*)d_in[1];
    const int*   track = (const int*)d_in[2];
    const int*   rs    = (const int*)d_in[3];

    int N = in_sizes[1];            // score flat count
    int F = in_sizes[0] / N;        // 32
    int B = in_sizes[3] - 1;        // 64
    int nb = (N + BS - 1) / BS;

    // workspace layout
    unsigned* seg_min = (unsigned*)d_ws;        // B
    int*      total   = (int*)(seg_min + B);    // 1
    int*      blk     = (int*)(total + 1);      // nb (counts -> exclusive offsets)

    // output layout (all stored as float32 values)
    float* out      = (float*)d_out;
    long off_rs   = (long)N * F;
    long off_old  = off_rs + (B + 1);
    long off_idx  = off_old + 1;
    long off_nsel = off_idx + N;

    float* out_rs   = out + off_rs;
    float* out_old  = out + off_old;
    float* out_idx  = out + off_idx;
    float* out_nsel = out + off_nsel;

    k_init<<<(B + BS - 1) / BS, BS, 0, stream>>>(seg_min, B);
    k_segmin<<<nb, BS, 0, stream>>>(score, track, rs, N, B, seg_min);
    k_count<<<nb, BS, 0, stream>>>(score, track, seg_min, B, N, blk);
    k_scan<<<1, SCAN_T, 0, stream>>>(blk, nb, total, out_old, out_nsel, N);
    k_newrs<<<B + 1, 64, 0, stream>>>(score, track, seg_min, B, rs, blk, total, nb, out_rs);

    bool vec = ((F & 3) == 0) && (BS % (F >> 2) == 0);
    if (vec) {
        int Fv = F >> 2;
        k_select<true><<<nb, BS, 0, stream>>>(score, track, seg_min, B, blk, total,
                                              N, Fv, (const float4*)x, (float4*)d_out, out_idx);
        long totElems = (long)N * Fv;
        int blocks = (int)((totElems + BS - 1) / BS);
        k_tailzero<<<blocks, BS, 0, stream>>>(total, totElems, Fv, (float4*)d_out);
    } else {
        k_select<false><<<nb, BS, 0, stream>>>(score, track, seg_min, B, blk, total,
                                               N, /*Fv*/1, nullptr, nullptr, out_idx);
        long tot = (long)N * F;
        int blocks = (int)((tot + BS - 1) / BS);
        k_gather1<<<blocks, BS, 0, stream>>>(x, out_idx, N, F, (float*)d_out);
    }
}